// Round 1
// 1265.257 us; speedup vs baseline: 1.2106x; 1.2106x over previous
//
#include <hip/hip_runtime.h>

// ============================================================================
// CNF log-density, fused persistent kernel — v2: occupancy restructure.
//   - Block = 256 thr / 4 waves / 32 rows = 2 row-groups x (2 waves N-split).
//     Per-wave accumulators halve (8 nt instead of 16) and RK k-state lives
//     in LDS slabs, cutting total regs to <256 so TWO blocks co-reside per CU
//     (2 waves/SIMD, independent barriers -> stall overlap).
//   - dz of stage s is written directly into LDS slab s by the layer-4
//     epilogue transpose; stage combines read k's from the slabs. Stage-6 dz
//     reuses k2's slab (k2 dead after the stage-6 input combine).
//   - Activation transpose buffer is shared by the 2 waves of a group
//     (disjoint column halves), with barriers between write/read phases.
// ============================================================================

#define DIM   64
#define HID   256
#define BATCH 32768
#define LOG2PI_HALF_SUM 58.8120661251f   // 32 * log(2*pi)

typedef float  floatx4 __attribute__((ext_vector_type(4)));
typedef short  short8  __attribute__((ext_vector_type(8)));

// ---- workspace layout (bytes) ----
#define W1OFF 0          // 2 kt * 16 nt * 1KB  = 32768
#define W2OFF 32768      // 8 kt * 16 nt * 1KB  = 131072
#define W3OFF 163840     // 131072
#define W4OFF 294912     // 8 kt * 4 nt * 1KB   = 32768
#define BOFF  327680     // biases fp32: b1[256] b2[256] b3[256] b4[64]

// ---- LDS layout (bytes) ----
#define BUF0 0
#define BUF1 8192
#define TBOFF 16384
#define TBSTRIDE 264                      // shorts per row (256 + 8 pad)
#define TBGROUP 8448                      // 16 * 264 * 2 bytes, per row-group
#define SLABOFF 33280                     // 16384 + 2*8448
#define SLABF 1088                        // floats per slab: 16 rows * 68
#define SLABGROUP (5 * SLABF)             // 5 slabs (k1..k5) per row-group
#define SMEM_BYTES 76800                  // 16384 + 16896 + 43520

__device__ __forceinline__ short f2bf(float f) {
    union { float f; unsigned u; } v; v.f = f;
    unsigned r = v.u + 0x7FFFu + ((v.u >> 16) & 1u);   // RTNE
    return (short)(r >> 16);
}

__device__ __forceinline__ float fast_tanh(float x) {
    float e = __expf(2.0f * x);
    return 1.0f - 2.0f * __builtin_amdgcn_rcpf(e + 1.0f);
}

template <int BYTES>
__device__ __forceinline__ void stage(const char* __restrict__ g, char* l) {
    const int t = threadIdx.x;
#pragma unroll
    for (int off = 0; off < BYTES; off += 4096) {
        *(uint4*)(l + off + t * 16) = *(const uint4*)(g + off + t * 16);
    }
}

// Shared (2 waves per group) activation transpose: in-place tanh on av, write
// bf16 h to the group's transpose buffer, barrier, read A-frags; then tangent.
__device__ __forceinline__ void act_transpose(floatx4* av, floatx4* at,
                                              short8* Av, short8* At,
                                              short* tbs, int m, int kq, int sw) {
#pragma unroll
    for (int ln = 0; ln < 8; ln++) {
        const int nt = (ln >> 2) * 8 + sw * 4 + (ln & 3);
#pragma unroll
        for (int i = 0; i < 4; i++) {
            float hv = fast_tanh(av[ln][i]);
            av[ln][i] = hv;                      // keep h for tangent scaling
            tbs[(kq * 4 + i) * TBSTRIDE + nt * 16 + m] = f2bf(hv);
        }
    }
    __syncthreads();
#pragma unroll
    for (int kt = 0; kt < 8; kt++)
        Av[kt] = *(const short8*)&tbs[m * TBSTRIDE + kt * 32 + kq * 8];
    __syncthreads();
#pragma unroll
    for (int ln = 0; ln < 8; ln++) {
        const int nt = (ln >> 2) * 8 + sw * 4 + (ln & 3);
#pragma unroll
        for (int i = 0; i < 4; i++) {
            float tv = (1.0f - av[ln][i] * av[ln][i]) * at[ln][i];
            tbs[(kq * 4 + i) * TBSTRIDE + nt * 16 + m] = f2bf(tv);
        }
    }
    __syncthreads();
#pragma unroll
    for (int kt = 0; kt < 8; kt++)
        At[kt] = *(const short8*)&tbs[m * TBSTRIDE + kt * 32 + kq * 8];
}

// One ODE f-eval. dz is written (fp32) into slab[slab_out] of this group's
// slab block; returns div = sum_k Jeps*eps for row (lane&15), replicated.
__device__ __forceinline__ float feval(short8 z0, short8 z1, short8 e0, short8 e1,
                                       const float* ef,
                                       const char* __restrict__ ws, char* smem,
                                       int slab_out) {
    const int tid  = threadIdx.x;
    const int lane = tid & 63;
    const int wave = tid >> 6;
    const int group = wave >> 1, sw = wave & 1;
    const int m  = lane & 15, kq = lane >> 4;
    char* bufs[2] = { smem + BUF0, smem + BUF1 };
    short* tbs = (short*)(smem + TBOFF + group * TBGROUP);
    float* tbf = (float*)tbs;
    float* slabf = (float*)(smem + SLABOFF) + group * SLABGROUP;
    const float* bias = (const float*)(ws + BOFF);
    const int boff = lane * 16;

    floatx4 av[8], at[8];
    short8  Av[8], At[8];
    const floatx4 zero4 = {0.f, 0.f, 0.f, 0.f};

    // ---------------- layer 1: K=64 (2 kt), N=256 ----------------
#pragma unroll
    for (int ln = 0; ln < 8; ln++) {
        const int nt = (ln >> 2) * 8 + sw * 4 + (ln & 3);
        float b = bias[nt * 16 + m];
        floatx4 bv = {b, b, b, b};
        av[ln] = bv; at[ln] = zero4;
    }
    stage<8192>(ws + W1OFF, bufs[0]);
    __syncthreads();
#pragma unroll
    for (int c = 0; c < 4; c++) {
        if (c < 3) stage<8192>(ws + W1OFF + (c + 1) * 8192, bufs[(c + 1) & 1]);
        short8 a_v = (c < 2) ? z0 : z1;
        short8 a_t = (c < 2) ? e0 : e1;
        const int hc = c & 1;
#pragma unroll
        for (int j = 0; j < 4; j++) {
            short8 b = *(const short8*)(bufs[c & 1] + (sw * 4 + j) * 1024 + boff);
            const int ln = hc * 4 + j;
            av[ln] = __builtin_amdgcn_mfma_f32_16x16x32_bf16(a_v, b, av[ln], 0, 0, 0);
            at[ln] = __builtin_amdgcn_mfma_f32_16x16x32_bf16(a_t, b, at[ln], 0, 0, 0);
        }
        __syncthreads();
    }
    act_transpose(av, at, Av, At, tbs, m, kq, sw);

    // ---------------- layers 2,3: K=256 (8 kt), N=256 ----------------
#pragma unroll 1
    for (int layer = 0; layer < 2; layer++) {
        const char* wb = ws + (layer ? W3OFF : W2OFF);
        const float* bb = bias + 256 + layer * 256;
#pragma unroll
        for (int ln = 0; ln < 8; ln++) {
            const int nt = (ln >> 2) * 8 + sw * 4 + (ln & 3);
            float b = bb[nt * 16 + m];
            floatx4 bv = {b, b, b, b};
            av[ln] = bv; at[ln] = zero4;
        }
        stage<8192>(wb, bufs[0]);
        __syncthreads();
#pragma unroll
        for (int c = 0; c < 16; c++) {
            if (c < 15) stage<8192>(wb + (c + 1) * 8192, bufs[(c + 1) & 1]);
            const int kt = c >> 1, hc = c & 1;
#pragma unroll
            for (int j = 0; j < 4; j++) {
                short8 b = *(const short8*)(bufs[c & 1] + (sw * 4 + j) * 1024 + boff);
                const int ln = hc * 4 + j;
                av[ln] = __builtin_amdgcn_mfma_f32_16x16x32_bf16(Av[kt], b, av[ln], 0, 0, 0);
                at[ln] = __builtin_amdgcn_mfma_f32_16x16x32_bf16(At[kt], b, at[ln], 0, 0, 0);
            }
            __syncthreads();
        }
        act_transpose(av, at, Av, At, tbs, m, kq, sw);
    }

    // ---------------- layer 4: K=256 (8 kt), N=64 ----------------
    floatx4 a4v[2], a4t[2];
#pragma unroll
    for (int j = 0; j < 2; j++) {
        float b = bias[768 + (sw * 2 + j) * 16 + m];
        floatx4 bv = {b, b, b, b};
        a4v[j] = bv; a4t[j] = zero4;
    }
    stage<4096>(ws + W4OFF, bufs[0]);
    __syncthreads();
#pragma unroll
    for (int kt = 0; kt < 8; kt++) {
        if (kt < 7) stage<4096>(ws + W4OFF + (kt + 1) * 4096, bufs[(kt + 1) & 1]);
#pragma unroll
        for (int j = 0; j < 2; j++) {
            short8 b = *(const short8*)(bufs[kt & 1] + (sw * 2 + j) * 1024 + boff);
            a4v[j] = __builtin_amdgcn_mfma_f32_16x16x32_bf16(Av[kt], b, a4v[j], 0, 0, 0);
            a4t[j] = __builtin_amdgcn_mfma_f32_16x16x32_bf16(At[kt], b, a4t[j], 0, 0, 0);
        }
        __syncthreads();
    }

    // Epilogue: Jeps (tangent) -> tbf temp; dz (value) -> k-slab slab_out.
    float* sl = slabf + slab_out * SLABF;
#pragma unroll
    for (int j = 0; j < 2; j++) {
        const int nt = sw * 2 + j;
#pragma unroll
        for (int i = 0; i < 4; i++) {
            tbf[(kq * 4 + i) * 68 + nt * 16 + m] = a4t[j][i];
            sl [(kq * 4 + i) * 68 + nt * 16 + m] = a4v[j][i];
        }
    }
    __syncthreads();
    float div = 0.f;
#pragma unroll
    for (int kt2 = 0; kt2 < 2; kt2++) {
#pragma unroll
        for (int jj = 0; jj < 8; jj += 4) {
            floatx4 jv = *(const floatx4*)&tbf[m * 68 + kt2 * 32 + kq * 8 + jj];
            div += jv.x * ef[kt2 * 8 + jj]     + jv.y * ef[kt2 * 8 + jj + 1]
                 + jv.z * ef[kt2 * 8 + jj + 2] + jv.w * ef[kt2 * 8 + jj + 3];
        }
    }
    div += __shfl_xor(div, 16, 64);
    div += __shfl_xor(div, 32, 64);
    return div;
}

// zs = y + sum_s cf[s]*k_s (k's from LDS slabs 0..NK-1), packed to bf16 frags.
template <int NK>
__device__ __forceinline__ void combine_pack(const float* y, const float (&cf)[NK],
                                             const float* slabf, int off,
                                             short8& lo, short8& hi) {
#pragma unroll
    for (int kt = 0; kt < 2; kt++) {
#pragma unroll
        for (int q = 0; q < 2; q++) {
            floatx4 a;
#pragma unroll
            for (int j = 0; j < 4; j++) a[j] = y[kt * 8 + q * 4 + j];
#pragma unroll
            for (int s = 0; s < NK; s++) {
                floatx4 v = *(const floatx4*)(slabf + s * SLABF + off + kt * 32 + q * 4);
#pragma unroll
                for (int j = 0; j < 4; j++) a[j] += cf[s] * v[j];
            }
#pragma unroll
            for (int j = 0; j < 4; j++) {
                if (kt == 0) lo[q * 4 + j] = f2bf(a[j]);
                else         hi[q * 4 + j] = f2bf(a[j]);
            }
        }
    }
}

__global__ void __launch_bounds__(256, 2)
cnf_main(const float* __restrict__ x, const float* __restrict__ eps,
         const char* __restrict__ ws, float* __restrict__ out) {
    extern __shared__ char smem[];
    const int tid  = threadIdx.x;
    const int lane = tid & 63;
    const int wave = tid >> 6;
    const int group = wave >> 1, sw = wave & 1;
    const int m  = lane & 15, kq = lane >> 4;
    const int row = blockIdx.x * 32 + group * 16 + m;
    float* slabf = (float*)(smem + SLABOFF) + group * SLABGROUP;
    const int koff = m * 68 + kq * 8;     // per-lane base within a slab

    float y[16], ef[16];
#pragma unroll
    for (int kt = 0; kt < 2; kt++)
#pragma unroll
        for (int q = 0; q < 2; q++) {
            floatx4 vx = *(const floatx4*)(x   + row * DIM + kt * 32 + kq * 8 + q * 4);
            floatx4 ve = *(const floatx4*)(eps + row * DIM + kt * 32 + kq * 8 + q * 4);
#pragma unroll
            for (int j = 0; j < 4; j++) {
                y[kt * 8 + q * 4 + j]  = vx[j];
                ef[kt * 8 + q * 4 + j] = ve[j];
            }
        }
    short8 e0, e1;
#pragma unroll
    for (int j = 0; j < 8; j++) { e0[j] = f2bf(ef[j]); e1[j] = f2bf(ef[8 + j]); }

    float ylogp = 0.f;
    short8 z0, z1;

#pragma unroll 1
    for (int step = 0; step < 4; step++) {
        // stage 1: input is y itself
#pragma unroll
        for (int j = 0; j < 8; j++) { z0[j] = f2bf(y[j]); z1[j] = f2bf(y[8 + j]); }
        const float d1 = feval(z0, z1, e0, e1, ef, ws, smem, 0);

        combine_pack<1>(y, {0.05f}, slabf, koff, z0, z1);
        const float d2 = feval(z0, z1, e0, e1, ef, ws, smem, 1);
        (void)d2;                                           // b2 = 0

        combine_pack<2>(y, {0.01875f, 0.05625f}, slabf, koff, z0, z1);
        const float d3 = feval(z0, z1, e0, e1, ef, ws, smem, 2);

        combine_pack<3>(y, {0.244444444f, -0.933333333f, 0.888888889f},
                        slabf, koff, z0, z1);
        const float d4 = feval(z0, z1, e0, e1, ef, ws, smem, 3);

        combine_pack<4>(y, {0.738149672f, -2.898948331f, 2.455723213f,
                            -0.072702332f}, slabf, koff, z0, z1);
        const float d5 = feval(z0, z1, e0, e1, ef, ws, smem, 4);

        combine_pack<5>(y, {0.711568813f, -2.689393939f, 2.226605679f,
                            0.069602273f, -0.068382826f}, slabf, koff, z0, z1);
        const float d6 = feval(z0, z1, e0, e1, ef, ws, smem, 1);  // k6 -> k2's slab

        // y += h * sum(b_i k_i);  slabs: k1=0, k3=2, k4=3, k5=4, k6=1
#pragma unroll
        for (int kt = 0; kt < 2; kt++)
#pragma unroll
            for (int q = 0; q < 2; q++) {
                const int o = koff + kt * 32 + q * 4;
                floatx4 k1v = *(const floatx4*)(slabf + 0 * SLABF + o);
                floatx4 k6v = *(const floatx4*)(slabf + 1 * SLABF + o);
                floatx4 k3v = *(const floatx4*)(slabf + 2 * SLABF + o);
                floatx4 k4v = *(const floatx4*)(slabf + 3 * SLABF + o);
                floatx4 k5v = *(const floatx4*)(slabf + 4 * SLABF + o);
#pragma unroll
                for (int j = 0; j < 4; j++)
                    y[kt * 8 + q * 4 + j] += 0.022786458f * k1v[j] + 0.112309075f * k3v[j]
                                           + 0.162760417f * k4v[j] - 0.080593989f * k5v[j]
                                           + 0.032738095f * k6v[j];
            }
        ylogp -= 0.022786458f * d1 + 0.112309075f * d3 + 0.162760417f * d4
               - 0.080593989f * d5 + 0.032738095f * d6;
    }

    float nrm = 0.f;
#pragma unroll
    for (int i = 0; i < 16; i++) nrm += y[i] * y[i];
    nrm += __shfl_xor(nrm, 16, 64);
    nrm += __shfl_xor(nrm, 32, 64);
    float res = -0.5f * nrm - LOG2PI_HALF_SUM - ylogp;
    if (sw == 0 && lane < 16) out[blockIdx.x * 32 + group * 16 + lane] = res;
}

// ---- weight pre-shuffle: fp32 [N][K] -> bf16 fragment-linear ----
__global__ void prep_w(const float* __restrict__ W, short* __restrict__ outp,
                       int K, int NT, int KT) {
    int slot  = blockIdx.x * 256 + threadIdx.x;
    int total = KT * NT * 64;
    if (slot >= total) return;
    int lane  = slot & 63, frag = slot >> 6;
    int ntile = frag % NT, ktile = frag / NT;
    int n = ntile * 16 + (lane & 15);
    int k = ktile * 32 + (lane >> 4) * 8;
    short8 v;
#pragma unroll
    for (int j = 0; j < 8; j++) v[j] = f2bf(W[n * K + k + j]);
    *(short8*)(outp + slot * 8) = v;
}

__global__ void prep_b(const float* __restrict__ b1, const float* __restrict__ b2,
                       const float* __restrict__ b3, const float* __restrict__ b4,
                       float* __restrict__ dst) {
    int i = blockIdx.x * 256 + threadIdx.x;
    if (i < 256)      dst[i] = b1[i];
    else if (i < 512) dst[i] = b2[i - 256];
    else if (i < 768) dst[i] = b3[i - 512];
    else if (i < 832) dst[i] = b4[i - 768];
}

extern "C" void kernel_launch(void* const* d_in, const int* in_sizes, int n_in,
                              void* d_out, int out_size, void* d_ws, size_t ws_size,
                              hipStream_t stream) {
    const float* x   = (const float*)d_in[0];
    const float* eps = (const float*)d_in[1];
    const float* W1  = (const float*)d_in[2];
    const float* b1  = (const float*)d_in[3];
    const float* W2  = (const float*)d_in[4];
    const float* b2  = (const float*)d_in[5];
    const float* W3  = (const float*)d_in[6];
    const float* b3  = (const float*)d_in[7];
    const float* W4  = (const float*)d_in[8];
    const float* b4  = (const float*)d_in[9];
    char*  ws  = (char*)d_ws;
    float* out = (float*)d_out;

    static bool attr_set = false;
    if (!attr_set) {
        hipFuncSetAttribute(reinterpret_cast<const void*>(cnf_main),
                            hipFuncAttributeMaxDynamicSharedMemorySize, SMEM_BYTES);
        attr_set = true;
    }

    prep_w<<<(2 * 16 * 64 + 255) / 256, 256, 0, stream>>>(W1, (short*)(ws + W1OFF), 64, 16, 2);
    prep_w<<<(8 * 16 * 64 + 255) / 256, 256, 0, stream>>>(W2, (short*)(ws + W2OFF), 256, 16, 8);
    prep_w<<<(8 * 16 * 64 + 255) / 256, 256, 0, stream>>>(W3, (short*)(ws + W3OFF), 256, 16, 8);
    prep_w<<<(8 * 4 * 64 + 255) / 256, 256, 0, stream>>>(W4, (short*)(ws + W4OFF), 256, 4, 8);
    prep_b<<<4, 256, 0, stream>>>(b1, b2, b3, b4, (float*)(ws + BOFF));

    cnf_main<<<BATCH / 32, 256, SMEM_BYTES, stream>>>(x, eps, ws, out);
}